// Round 11
// baseline (207.092 us; speedup 1.0000x reference)
//
#include <hip/hip_runtime.h>

typedef _Float16 half8  __attribute__((ext_vector_type(8)));
typedef _Float16 half4_t __attribute__((ext_vector_type(4)));
typedef float    f32x4  __attribute__((ext_vector_type(4)));

#define B_SZ    64
#define S_SZ    4096
#define H_SZ    256
#define CHUNKS  8
#define SCHUNK  512
#define TILE_R  32
#define NTILES  (SCHUNK / TILE_R)   // 16
#define PAD_H   264                 // row stride 132 words

__device__ __forceinline__ float tanh_fast(float x) {
  // 1 - 2/(e^{2x}+1); rcpf: +inf -> 1, -inf -> -1, no NaN
  return 1.f - 2.f * __builtin_amdgcn_rcpf(__expf(2.f * x) + 1.f);
}

// LDS-visibility barrier that does NOT drain vmcnt: global prefetch stays in flight.
__device__ __forceinline__ void lds_barrier() {
  asm volatile("s_waitcnt lgkmcnt(0)" ::: "memory");
  __builtin_amdgcn_s_barrier();
}

// After shl8,shl4,shl2,shl1 (bound_ctrl zero-fill): lane 0 of each 16-lane row = row sum.
template<int CTRL>
__device__ __forceinline__ float dpp_add_shl(float x) {
  int s = __builtin_amdgcn_update_dpp(0, __builtin_bit_cast(int, x), CTRL, 0xf, 0xf, true);
  return x + __builtin_bit_cast(float, s);
}
__device__ __forceinline__ float row_reduce16(float x) {
  x = dpp_add_shl<0x108>(x);  // row_shl:8
  x = dpp_add_shl<0x104>(x);  // row_shl:4
  x = dpp_add_shl<0x102>(x);  // row_shl:2
  x = dpp_add_shl<0x101>(x);  // row_shl:1
  return x;
}

// ---------------- kernel 0: bias[b][k] = fh[b]·W2[k]; also zero merge counters ----------
__global__ __launch_bounds__(256) void bias_kernel(const float* __restrict__ fh,
                                                   const float* __restrict__ W2,
                                                   float* __restrict__ bias,
                                                   int* __restrict__ cnt) {
  const int b = blockIdx.x, k = threadIdx.x;
  if (k == 0) cnt[b] = 0;
  __shared__ float fsh[H_SZ];
  fsh[k] = fh[b * H_SZ + k];
  __syncthreads();
  const float* wrow = W2 + (size_t)k * H_SZ;
  float s = 0.f;
#pragma unroll 4
  for (int h = 0; h < H_SZ; h += 4) {
    f32x4 w = *(const f32x4*)(wrow + h);
    s += w[0] * fsh[h] + w[1] * fsh[h + 1] + w[2] * fsh[h + 2] + w[3] * fsh[h + 3];
  }
  bias[b * H_SZ + k] = s;
}

// ---------------- kernel 1: fused; loads spread through compute; tail-block merge --------
// grid 512 = 64 b * 8 chunks; block 512 = 8 waves. Wave w owns proj cols [32w, 32w+32).
// Per t: stage(t)<-ldbuf; barrier; rf0 MFMA; issue ld[0..1](t+2); rf0 score;
//        rf1 MFMA; issue ld[2..3](t+2); rf1 score; context(t-1).
__global__ __launch_bounds__(512, 2) void fused_kernel(const float* __restrict__ enc,
                                                       const float* __restrict__ W1,
                                                       const float* __restrict__ v,
                                                       const float* __restrict__ bias,
                                                       float* __restrict__ pc,   // [512][256]
                                                       float* __restrict__ pl,   // [512]
                                                       int* __restrict__ cnt,    // [64]
                                                       float* __restrict__ out) {
  __shared__ _Float16 As[3][TILE_R][PAD_H] __attribute__((aligned(16)));  // 49.5 KB
  __shared__ float spartT[2][TILE_R][12];  // score partials, double-buffered
  __shared__ float cpart[8][H_SZ];         // epilogue context merge
  __shared__ float lArr[8];
  __shared__ int winner;

  const int tid  = threadIdx.x;
  const int wave = tid >> 6;
  const int lane = tid & 63;
  const int nlo  = lane & 15;
  const int g    = lane >> 4;
  const int khi  = g * 8;
  const int b     = blockIdx.x >> 3;
  const int chunk = blockIdx.x & 7;
  const size_t encBase = ((size_t)b * S_SZ + (size_t)chunk * SCHUNK) * H_SZ;
  const float* src0 = enc + encBase + (size_t)tid * 4;

  // prologue: issue tile-0 loads FIRST (critical stream)
  f32x4 ldA[4], ldB[4];
#pragma unroll
  for (int i = 0; i < 4; ++i) ldA[i] = *(const f32x4*)(src0 + i * 2048);

  // ---- W1 fragments in registers: B[k=h][n=col]; lane l holds col wave*32+cf*16+nlo
  half8 wf[2][8];
#pragma unroll
  for (int cf = 0; cf < 2; ++cf) {
    const int n = wave * 32 + cf * 16 + nlo;
    const float* wrow = W1 + (size_t)n * H_SZ + khi;
#pragma unroll
    for (int ks = 0; ks < 8; ++ks) {
      f32x4 w0 = *(const f32x4*)(wrow + ks * 32);
      f32x4 w1 = *(const f32x4*)(wrow + ks * 32 + 4);
      half8 h;
#pragma unroll
      for (int j = 0; j < 4; ++j) { h[j] = (_Float16)w0[j]; h[4 + j] = (_Float16)w1[j]; }
      wf[cf][ks] = h;
    }
  }
  // issue tile-1 loads (second buffer)
#pragma unroll
  for (int i = 0; i < 4; ++i) ldB[i] = *(const f32x4*)(src0 + TILE_R * H_SZ + i * 2048);

  const int n0c = wave * 32 + nlo;
  const float vv0 = v[n0c],               vv1 = v[n0c + 16];
  const float bv0 = bias[b * H_SZ + n0c], bv1 = bias[b * H_SZ + n0c + 16];

  float l_acc = 0.f;
  float c0 = 0.f, c1 = 0.f, c2 = 0.f, c3 = 0.f;  // context h-slice: h = 4*lane..+3

  int p = 0;        // t % 3
  int pm1 = 2;      // (t-1) % 3

  // one tile-iteration; ld holds tile t, re-issued (spread through compute) for tile t+2
  auto tile_iter = [&](int t, f32x4 (&ld)[4]) {
    // stage(t): consume ld -> As[p]
#pragma unroll
    for (int i = 0; i < 4; ++i) {
      const int f4 = tid + i * 512;
      const int r = f4 >> 6, hq = (f4 & 63) * 4;
      half4_t hv;
      hv[0] = (_Float16)ld[i][0]; hv[1] = (_Float16)ld[i][1];
      hv[2] = (_Float16)ld[i][2]; hv[3] = (_Float16)ld[i][3];
      *(half4_t*)&As[p][r][hq] = hv;
    }
    lds_barrier();   // As[p] + spartT[(t-1)&1] visible; prior prefetch stays in flight

    const bool pf = (t + 2 < NTILES);
    const float* srcN = src0 + (size_t)(t + 2) * TILE_R * H_SZ;

    // ---- rf0: MFMA chain, then issue 2 prefetch loads, then score
    {
      f32x4 d0 = {bv0, bv0, bv0, bv0}, d1 = {bv1, bv1, bv1, bv1};
#pragma unroll
      for (int ks = 0; ks < 8; ++ks) {
        half8 a = *(const half8*)&As[p][nlo][ks * 32 + khi];
        d0 = __builtin_amdgcn_mfma_f32_16x16x32_f16(a, wf[0][ks], d0, 0, 0, 0);
        d1 = __builtin_amdgcn_mfma_f32_16x16x32_f16(a, wf[1][ks], d1, 0, 0, 0);
      }
      if (pf) {   // issue point 1 (regs dead since stage)
        ld[0] = *(const f32x4*)(srcN);
        ld[1] = *(const f32x4*)(srcN + 2048);
      }
      f32x4 s4;
#pragma unroll
      for (int i = 0; i < 4; ++i)
        s4[i] = tanh_fast(d0[i]) * vv0 + tanh_fast(d1[i]) * vv1;
#pragma unroll
      for (int i = 0; i < 4; ++i) s4[i] = row_reduce16(s4[i]);
      if (nlo == 0) {
#pragma unroll
        for (int i = 0; i < 4; ++i) spartT[t & 1][g * 4 + i][wave] = s4[i];
      }
    }
    // ---- rf1: MFMA chain, then issue remaining 2 loads, then score
    {
      f32x4 d0 = {bv0, bv0, bv0, bv0}, d1 = {bv1, bv1, bv1, bv1};
#pragma unroll
      for (int ks = 0; ks < 8; ++ks) {
        half8 a = *(const half8*)&As[p][16 + nlo][ks * 32 + khi];
        d0 = __builtin_amdgcn_mfma_f32_16x16x32_f16(a, wf[0][ks], d0, 0, 0, 0);
        d1 = __builtin_amdgcn_mfma_f32_16x16x32_f16(a, wf[1][ks], d1, 0, 0, 0);
      }
      if (pf) {   // issue point 2
        ld[2] = *(const f32x4*)(srcN + 4096);
        ld[3] = *(const f32x4*)(srcN + 6144);
      }
      f32x4 s4;
#pragma unroll
      for (int i = 0; i < 4; ++i)
        s4[i] = tanh_fast(d0[i]) * vv0 + tanh_fast(d1[i]) * vv1;
#pragma unroll
      for (int i = 0; i < 4; ++i) s4[i] = row_reduce16(s4[i]);
      if (nlo == 0) {
#pragma unroll
        for (int i = 0; i < 4; ++i) spartT[t & 1][16 + g * 4 + i][wave] = s4[i];
      }
    }

    // ---- context(t-1): rows [4w, 4w+4) of As[pm1]; spartT[(t-1)&1] (1 barrier old)
    if (t > 0) {
#pragma unroll
      for (int rr = 0; rr < 4; ++rr) {
        const int r = wave * 4 + rr;
        const f32x4 q0 = *(const f32x4*)&spartT[(t - 1) & 1][r][0];  // broadcast reads
        const f32x4 q1 = *(const f32x4*)&spartT[(t - 1) & 1][r][4];
        const float u = __expf(q0[0] + q0[1] + q0[2] + q0[3] + q1[0] + q1[1] + q1[2] + q1[3]);
        l_acc += u;
        half4_t a = *(const half4_t*)&As[pm1][r][lane * 4];
        c0 += u * (float)a[0];
        c1 += u * (float)a[1];
        c2 += u * (float)a[2];
        c3 += u * (float)a[3];
      }
    }
    pm1 = p;
    p = (p == 2) ? 0 : p + 1;
  };

#pragma unroll 1
  for (int t2 = 0; t2 < NTILES; t2 += 2) {
    tile_iter(t2,     ldA);
    tile_iter(t2 + 1, ldB);
  }

  // ---- drain: context(NTILES-1)
  lds_barrier();
  {
    const int tl = (NTILES - 1) & 1;
#pragma unroll
    for (int rr = 0; rr < 4; ++rr) {
      const int r = wave * 4 + rr;
      const f32x4 q0 = *(const f32x4*)&spartT[tl][r][0];
      const f32x4 q1 = *(const f32x4*)&spartT[tl][r][4];
      const float u = __expf(q0[0] + q0[1] + q0[2] + q0[3] + q1[0] + q1[1] + q1[2] + q1[3]);
      l_acc += u;
      half4_t a = *(const half4_t*)&As[pm1][r][lane * 4];
      c0 += u * (float)a[0];
      c1 += u * (float)a[1];
      c2 += u * (float)a[2];
      c3 += u * (float)a[3];
    }
  }

  // ---- epilogue: merge 8 waves -> chunk partial
  {
    f32x4 cv; cv[0] = c0; cv[1] = c1; cv[2] = c2; cv[3] = c3;
    *(f32x4*)&cpart[wave][lane * 4] = cv;
  }
  if (lane == 0) lArr[wave] = l_acc;
  __syncthreads();
  if (tid < H_SZ) {
    float s = 0.f;
#pragma unroll
    for (int w = 0; w < 8; ++w) s += cpart[w][tid];
    pc[(size_t)blockIdx.x * H_SZ + tid] = s;
  }
  if (tid == 0) {
    float L = 0.f;
#pragma unroll
    for (int w = 0; w < 8; ++w) L += lArr[w];
    pl[blockIdx.x] = L;
  }

  // ---- tail-block merge (replaces combine kernel; order-independent sums -> deterministic)
  __threadfence();   // release pc/pl to device scope
  if (tid == 0) {
    const int old = atomicAdd(&cnt[b], 1);
    winner = (old == CHUNKS - 1) ? 1 : 0;
  }
  __syncthreads();
  if (winner) {
    __threadfence();  // acquire other blocks' pc/pl
    if (tid < H_SZ) {
      float L = 0.f, s = 0.f;
#pragma unroll
      for (int j = 0; j < CHUNKS; ++j) {
        L += pl[b * CHUNKS + j];
        s += pc[(size_t)(b * CHUNKS + j) * H_SZ + tid];
      }
      out[b * H_SZ + tid] = s / L;
    }
  }
}

extern "C" void kernel_launch(void* const* d_in, const int* in_sizes, int n_in,
                              void* d_out, int out_size, void* d_ws, size_t ws_size,
                              hipStream_t stream) {
  const float* enc = (const float*)d_in[0];  // [64,4096,256]
  const float* fh  = (const float*)d_in[1];  // [64,256]
  const float* W1  = (const float*)d_in[2];  // [256,256]
  const float* W2  = (const float*)d_in[3];  // [256,256]
  const float* v   = (const float*)d_in[4];  // [256]
  float* out = (float*)d_out;                // [64,256]

  float* ws   = (float*)d_ws;
  float* bias = ws;                          // 64*256
  float* pc   = ws + B_SZ * H_SZ;            // 512*256
  float* pl   = pc + B_SZ * CHUNKS * H_SZ;   // 512
  int*   cnt  = (int*)(pl + B_SZ * CHUNKS);  // 64

  bias_kernel<<<B_SZ, H_SZ, 0, stream>>>(fh, W2, bias, cnt);
  fused_kernel<<<B_SZ * CHUNKS, 512, 0, stream>>>(enc, W1, v, bias, pc, pl, cnt, out);
}

// Round 12
// 86.044 us; speedup vs baseline: 2.4068x; 2.4068x over previous
//
#include <hip/hip_runtime.h>

typedef _Float16 half8  __attribute__((ext_vector_type(8)));
typedef _Float16 half4_t __attribute__((ext_vector_type(4)));
typedef float    f32x4  __attribute__((ext_vector_type(4)));
typedef unsigned int uint2_t __attribute__((ext_vector_type(2)));

#define B_SZ    64
#define S_SZ    4096
#define H_SZ    256
#define CHUNKS  8
#define SCHUNK  512
#define TILE_R  32
#define NTILES  (SCHUNK / TILE_R)   // 16
#define PAD_H   264                 // row stride 132 words

__device__ __forceinline__ float tanh_fast(float x) {
  // 1 - 2/(e^{2x}+1); rcpf: +inf -> 1, -inf -> -1, no NaN
  return 1.f - 2.f * __builtin_amdgcn_rcpf(__expf(2.f * x) + 1.f);
}

// LDS-visibility barrier that does NOT drain vmcnt: global prefetch stays in flight.
__device__ __forceinline__ void lds_barrier() {
  asm volatile("s_waitcnt lgkmcnt(0)" ::: "memory");
  __builtin_amdgcn_s_barrier();
}

// After shl8,shl4,shl2,shl1 (bound_ctrl zero-fill): lane 0 of each 16-lane row = row sum.
template<int CTRL>
__device__ __forceinline__ float dpp_add_shl(float x) {
  int s = __builtin_amdgcn_update_dpp(0, __builtin_bit_cast(int, x), CTRL, 0xf, 0xf, true);
  return x + __builtin_bit_cast(float, s);
}
__device__ __forceinline__ float row_reduce16(float x) {
  x = dpp_add_shl<0x108>(x);  // row_shl:8
  x = dpp_add_shl<0x104>(x);  // row_shl:4
  x = dpp_add_shl<0x102>(x);  // row_shl:2
  x = dpp_add_shl<0x101>(x);  // row_shl:1
  return x;
}

// ---------------- kernel 0: bias[b][k] = sum_h final_h[b][h] * W2[k][h] ----------------
__global__ __launch_bounds__(256) void bias_kernel(const float* __restrict__ fh,
                                                   const float* __restrict__ W2,
                                                   float* __restrict__ bias) {
  const int b = blockIdx.x, k = threadIdx.x;
  __shared__ float fsh[H_SZ];
  fsh[k] = fh[b * H_SZ + k];
  __syncthreads();
  const float* wrow = W2 + (size_t)k * H_SZ;
  float s = 0.f;
#pragma unroll 4
  for (int h = 0; h < H_SZ; h += 4) {
    f32x4 w = *(const f32x4*)(wrow + h);
    s += w[0] * fsh[h] + w[1] * fsh[h + 1] + w[2] * fsh[h + 2] + w[3] * fsh[h + 3];
  }
  bias[b * H_SZ + k] = s;
}

// ---------------- kernel 1: fused; 1 barrier/tile; 2-deep register prefetch -------------
// grid 512 = 64 b * 8 chunks; block 512 = 8 waves. Wave w owns proj cols [32w, 32w+32).
// Per t: stage(t)<-ldbuf[t&1]; reissue ldbuf[t&1]<-loads(t+2); barrier;
//        MFMA+score(t)->spartT[t&1] ; context(t-1) from As[pm1]+spartT[(t-1)&1].
__global__ __launch_bounds__(512, 2) void fused_kernel(const float* __restrict__ enc,
                                                       const float* __restrict__ W1,
                                                       const float* __restrict__ v,
                                                       const float* __restrict__ bias,
                                                       float* __restrict__ pc,   // [512][256]
                                                       float* __restrict__ pl) { // [512]
  __shared__ _Float16 As[3][TILE_R][PAD_H] __attribute__((aligned(16)));  // 49.5 KB
  __shared__ float spartT[2][TILE_R][12];  // score partials, double-buffered
  __shared__ float cpart[8][H_SZ];         // epilogue context merge
  __shared__ float lArr[8];

  const int tid  = threadIdx.x;
  const int wave = tid >> 6;
  const int lane = tid & 63;
  const int nlo  = lane & 15;
  const int g    = lane >> 4;
  const int khi  = g * 8;
  const int b     = blockIdx.x >> 3;
  const int chunk = blockIdx.x & 7;
  const size_t encBase = ((size_t)b * S_SZ + (size_t)chunk * SCHUNK) * H_SZ;
  const float* src0 = enc + encBase + (size_t)tid * 4;

  // prologue: issue tile-0 loads FIRST (critical stream)
  f32x4 ldA[4], ldB[4];
#pragma unroll
  for (int i = 0; i < 4; ++i) ldA[i] = *(const f32x4*)(src0 + i * 2048);

  // ---- W1 fragments in registers: B[k=h][n=col]; lane l holds col wave*32+cf*16+nlo
  half8 wf[2][8];
#pragma unroll
  for (int cf = 0; cf < 2; ++cf) {
    const int n = wave * 32 + cf * 16 + nlo;
    const float* wrow = W1 + (size_t)n * H_SZ + khi;
#pragma unroll
    for (int ks = 0; ks < 8; ++ks) {
      f32x4 w0 = *(const f32x4*)(wrow + ks * 32);
      f32x4 w1 = *(const f32x4*)(wrow + ks * 32 + 4);
      half8 h;
#pragma unroll
      for (int j = 0; j < 4; ++j) { h[j] = (_Float16)w0[j]; h[4 + j] = (_Float16)w1[j]; }
      wf[cf][ks] = h;
    }
  }
  // issue tile-1 loads (second buffer)
#pragma unroll
  for (int i = 0; i < 4; ++i) ldB[i] = *(const f32x4*)(src0 + TILE_R * H_SZ + i * 2048);

  const int n0c = wave * 32 + nlo;
  const float vv0 = v[n0c],               vv1 = v[n0c + 16];
  const float bv0 = bias[b * H_SZ + n0c], bv1 = bias[b * H_SZ + n0c + 16];

  float l_acc = 0.f;
  float c0 = 0.f, c1 = 0.f, c2 = 0.f, c3 = 0.f;  // context h-slice: h = 4*lane..+3

  int p = 0;        // t % 3
  int pm1 = 2;      // (t-1) % 3

  // one tile-iteration; ld is the buffer holding tile t, re-issued for tile t+2
  auto tile_iter = [&](int t, f32x4 (&ld)[4]) {
    // stage(t): consume ld -> As[p] via pack-RTZ (2 VALU per f32x4)
#pragma unroll
    for (int i = 0; i < 4; ++i) {
      const int f4 = tid + i * 512;
      const int r = f4 >> 6, hq = (f4 & 63) * 4;
      uint2_t hv;
      hv[0] = __builtin_bit_cast(unsigned int, __builtin_amdgcn_cvt_pkrtz(ld[i][0], ld[i][1]));
      hv[1] = __builtin_bit_cast(unsigned int, __builtin_amdgcn_cvt_pkrtz(ld[i][2], ld[i][3]));
      *(uint2_t*)&As[p][r][hq] = hv;
    }
    // re-issue this buffer for tile t+2 (2 tiles always in flight)
    if (t + 2 < NTILES) {
      const float* srcN = src0 + (size_t)(t + 2) * TILE_R * H_SZ;
#pragma unroll
      for (int i = 0; i < 4; ++i) ld[i] = *(const f32x4*)(srcN + i * 2048);
    }
    lds_barrier();   // As[p] + spartT[(t-1)&1] visible; prefetch stays in flight

    // ---- MFMA+score(t): proj tile [32 x 32(this wave)] (bias in acc init)
#pragma unroll
    for (int rf = 0; rf < 2; ++rf) {
      f32x4 d0 = {bv0, bv0, bv0, bv0}, d1 = {bv1, bv1, bv1, bv1};
#pragma unroll
      for (int ks = 0; ks < 8; ++ks) {
        half8 a = *(const half8*)&As[p][rf * 16 + nlo][ks * 32 + khi];
        d0 = __builtin_amdgcn_mfma_f32_16x16x32_f16(a, wf[0][ks], d0, 0, 0, 0);
        d1 = __builtin_amdgcn_mfma_f32_16x16x32_f16(a, wf[1][ks], d1, 0, 0, 0);
      }
      f32x4 s4;
#pragma unroll
      for (int i = 0; i < 4; ++i)
        s4[i] = tanh_fast(d0[i]) * vv0 + tanh_fast(d1[i]) * vv1;
#pragma unroll
      for (int i = 0; i < 4; ++i) s4[i] = row_reduce16(s4[i]);
      if (nlo == 0) {  // lanes 0,16,32,48: rows rf*16 + g*4 + i
#pragma unroll
        for (int i = 0; i < 4; ++i) spartT[t & 1][rf * 16 + g * 4 + i][wave] = s4[i];
      }
    }

    // ---- context(t-1): rows [4w, 4w+4) of As[pm1]; spartT[(t-1)&1] (1 barrier old)
    if (t > 0) {
#pragma unroll
      for (int rr = 0; rr < 4; ++rr) {
        const int r = wave * 4 + rr;
        const f32x4 q0 = *(const f32x4*)&spartT[(t - 1) & 1][r][0];  // broadcast reads
        const f32x4 q1 = *(const f32x4*)&spartT[(t - 1) & 1][r][4];
        const float u = __expf(q0[0] + q0[1] + q0[2] + q0[3] + q1[0] + q1[1] + q1[2] + q1[3]);
        l_acc += u;
        half4_t a = *(const half4_t*)&As[pm1][r][lane * 4];
        c0 += u * (float)a[0];
        c1 += u * (float)a[1];
        c2 += u * (float)a[2];
        c3 += u * (float)a[3];
      }
    }
    pm1 = p;
    p = (p == 2) ? 0 : p + 1;
  };

#pragma unroll 1
  for (int t2 = 0; t2 < NTILES; t2 += 2) {
    tile_iter(t2,     ldA);
    tile_iter(t2 + 1, ldB);
  }

  // ---- drain: context(NTILES-1)
  lds_barrier();
  {
    const int tl = (NTILES - 1) & 1;
#pragma unroll
    for (int rr = 0; rr < 4; ++rr) {
      const int r = wave * 4 + rr;
      const f32x4 q0 = *(const f32x4*)&spartT[tl][r][0];
      const f32x4 q1 = *(const f32x4*)&spartT[tl][r][4];
      const float u = __expf(q0[0] + q0[1] + q0[2] + q0[3] + q1[0] + q1[1] + q1[2] + q1[3]);
      l_acc += u;
      half4_t a = *(const half4_t*)&As[pm1][r][lane * 4];
      c0 += u * (float)a[0];
      c1 += u * (float)a[1];
      c2 += u * (float)a[2];
      c3 += u * (float)a[3];
    }
  }

  // ---- epilogue: merge 8 waves
  {
    f32x4 cv; cv[0] = c0; cv[1] = c1; cv[2] = c2; cv[3] = c3;
    *(f32x4*)&cpart[wave][lane * 4] = cv;
  }
  if (lane == 0) lArr[wave] = l_acc;
  __syncthreads();
  if (tid < H_SZ) {
    float s = 0.f;
#pragma unroll
    for (int w = 0; w < 8; ++w) s += cpart[w][tid];
    pc[(size_t)blockIdx.x * H_SZ + tid] = s;
  }
  if (tid == 0) {
    float L = 0.f;
#pragma unroll
    for (int w = 0; w < 8; ++w) L += lArr[w];
    pl[blockIdx.x] = L;
  }
}

// ---------------- kernel 2: merge 8 chunk partials per batch (plain sums) ----------------
__global__ __launch_bounds__(256) void combine_kernel(const float* __restrict__ pc,
                                                      const float* __restrict__ pl,
                                                      float* __restrict__ out) {
  const int b = blockIdx.x, h = threadIdx.x;
  float L = 0.f, s = 0.f;
#pragma unroll
  for (int j = 0; j < CHUNKS; ++j) {
    L += pl[b * CHUNKS + j];
    s += pc[(size_t)(b * CHUNKS + j) * H_SZ + h];
  }
  out[b * H_SZ + h] = s / L;
}

extern "C" void kernel_launch(void* const* d_in, const int* in_sizes, int n_in,
                              void* d_out, int out_size, void* d_ws, size_t ws_size,
                              hipStream_t stream) {
  const float* enc = (const float*)d_in[0];  // [64,4096,256]
  const float* fh  = (const float*)d_in[1];  // [64,256]
  const float* W1  = (const float*)d_in[2];  // [256,256]
  const float* W2  = (const float*)d_in[3];  // [256,256]
  const float* v   = (const float*)d_in[4];  // [256]
  float* out = (float*)d_out;                // [64,256]

  float* ws   = (float*)d_ws;
  float* bias = ws;                          // 64*256
  float* pc   = ws + B_SZ * H_SZ;            // 512*256
  float* pl   = pc + B_SZ * CHUNKS * H_SZ;   // 512

  bias_kernel<<<B_SZ, H_SZ, 0, stream>>>(fh, W2, bias);
  fused_kernel<<<B_SZ * CHUNKS, 512, 0, stream>>>(enc, W1, v, bias, pc, pl);
  combine_kernel<<<B_SZ, H_SZ, 0, stream>>>(pc, pl, out);
}